// Round 2
// baseline (562.852 us; speedup 1.0000x reference)
//
#include <hip/hip_runtime.h>
#include <hip/hip_fp16.h>

// CapsNet dynamic routing, B=256, P=2048, C=10, OUT=16, IN=8, 3 iters.
// K1: u_hat[b,p,c,o] = sum_i W[p,c,o,i]*u[b,p,i]  -> fp16 in d_ws (167.8 MB)
// K2: one block per b (512 thr); 3 fused passes over u_hat (iter-k b-update
//     folded into iter-k softmax + s accumulation). logits fp16 in LDS.
// R2 fix: R1's rotated LDS-atomic reduction was wrong (added s_part[k] into
// s_lds[(k+3*lane)%160]). Replaced with shfl_xor butterfly + per-wave s_red
// rows + 160-thread gather — correct by construction.

#define Bn 256
#define Pn 2048
#define Cn 10
#define On 16
#define In 8
#define ROW (Cn * On) // 160
#define TPB 512       // k_route threads (8 waves, 2/SIMD)
#define RPT (Pn / TPB) // 4 rows per thread
#define NW (TPB / 64)  // 8 waves

__global__ __launch_bounds__(256) void k_uhat(const float* __restrict__ u,
                                              const float* __restrict__ W,
                                              __half* __restrict__ uhat) {
  const int p = blockIdx.x;  // W index is wave-uniform -> scalar loads
  const int b = threadIdx.x;
  const float4* up = reinterpret_cast<const float4*>(u + ((size_t)b * Pn + p) * In);
  float4 a0 = up[0];
  float4 a1 = up[1];
  const float uu[8] = {a0.x, a0.y, a0.z, a0.w, a1.x, a1.y, a1.z, a1.w};
  __half* orow = uhat + ((size_t)b * Pn + p) * ROW;
  const float* wb = W + (size_t)p * (Cn * On * In);
#pragma unroll
  for (int c = 0; c < Cn; ++c) {
    const float* wr = wb + c * (On * In);
    union { float4 f[2]; __half2 h2[8]; } pk;
#pragma unroll
    for (int o2 = 0; o2 < 8; ++o2) {
      float acc0 = 0.f, acc1 = 0.f;
#pragma unroll
      for (int i = 0; i < In; ++i) {
        acc0 = __builtin_fmaf(wr[(2 * o2) * In + i], uu[i], acc0);
        acc1 = __builtin_fmaf(wr[(2 * o2 + 1) * In + i], uu[i], acc1);
      }
      pk.h2[o2] = __floats2half2_rn(acc0, acc1);
    }
    float4* dst = reinterpret_cast<float4*>(orow + c * On);
    dst[0] = pk.f[0];
    dst[1] = pk.f[1];
  }
}

__device__ __forceinline__ void load_row16(const __half* rp, float (&v)[On]) {
  union { float4 f; __half2 h2[4]; } q0, q1;
  q0.f = *reinterpret_cast<const float4*>(rp);
  q1.f = *reinterpret_cast<const float4*>(rp + 8);
#pragma unroll
  for (int t = 0; t < 4; ++t) {
    float2 lo = __half22float2(q0.h2[t]);
    float2 hi = __half22float2(q1.h2[t]);
    v[2 * t] = lo.x;
    v[2 * t + 1] = lo.y;
    v[8 + 2 * t] = hi.x;
    v[8 + 2 * t + 1] = hi.y;
  }
}

// Butterfly-reduce each element across the wave, deposit per-wave sums into
// s_red, gather across waves, scale, squash into v_lds. 3 barriers.
__device__ __forceinline__ void reduce_squash(float (&s_part)[ROW], float scale,
                                              int tid, int lane, int w,
                                              float (*s_red)[ROW],
                                              float* s_lds, float* v_lds) {
#pragma unroll
  for (int k = 0; k < ROW; ++k) {
    float x = s_part[k];
#pragma unroll
    for (int off = 32; off >= 1; off >>= 1) x += __shfl_xor(x, off, 64);
    if ((k & 63) == lane) s_red[w][k] = x;  // one lane per wave per element
  }
  __syncthreads();
  if (tid < ROW) {
    float t = 0.f;
#pragma unroll
    for (int ww = 0; ww < NW; ++ww) t += s_red[ww][tid];
    s_lds[tid] = scale * t;
  }
  __syncthreads();
  if (tid < Cn) {
    float sq = 0.f;
#pragma unroll
    for (int o = 0; o < On; ++o) {
      float x = s_lds[tid * On + o];
      sq += x * x;
    }
    float sc = (sq / (1.f + sq)) / sqrtf(sq + 1e-9f);
#pragma unroll
    for (int o = 0; o < On; ++o) v_lds[tid * On + o] = sc * s_lds[tid * On + o];
  }
  __syncthreads();
}

__global__ __launch_bounds__(TPB, 2) void k_route(const __half* __restrict__ uhat,
                                                  float* __restrict__ out) {
  __shared__ __half logits_h[Pn][Cn]; // 40 KB
  __shared__ float s_red[NW][ROW];    // 5 KB
  __shared__ float s_lds[ROW];
  __shared__ float v_lds[ROW];
  const int b = blockIdx.x;
  const int tid = threadIdx.x;
  const int lane = tid & 63;
  const int w = tid >> 6;
  const __half* base = uhat + (size_t)b * Pn * ROW;

  float s_part[ROW];

  // ---------- PASS 1: c uniform = 1/10 (softmax of zeros) ----------
#pragma unroll
  for (int k = 0; k < ROW; ++k) s_part[k] = 0.f;
  for (int j = 0; j < RPT; ++j) {
    const __half* row = base + (size_t)(tid + TPB * j) * ROW;
#pragma unroll
    for (int c = 0; c < Cn; ++c) {
      float v16[On];
      load_row16(row + c * On, v16);
#pragma unroll
      for (int o = 0; o < On; ++o) s_part[c * On + o] += v16[o];
    }
  }
  reduce_squash(s_part, 0.1f, tid, lane, w, s_red, s_lds, v_lds);

  // ---------- PASSES 2 and 3 (b-update folded into softmax) ----------
  for (int pass = 0; pass < 2; ++pass) {
#pragma unroll
    for (int k = 0; k < ROW; ++k) s_part[k] = 0.f;
    for (int j = 0; j < RPT; ++j) {
      const int p = tid + TPB * j;
      const __half* row = base + (size_t)p * ROW;
      float lg[Cn];
#pragma unroll
      for (int c = 0; c < Cn; ++c) {
        float v16[On];
        load_row16(row + c * On, v16);
        float d = 0.f;
#pragma unroll
        for (int o = 0; o < On; ++o) d = __builtin_fmaf(v16[o], v_lds[c * On + o], d);
        lg[c] = (pass == 0) ? d : (d + __half2float(logits_h[p][c]));
      }
      if (pass == 0) {
#pragma unroll
        for (int c = 0; c < Cn; ++c) logits_h[p][c] = __float2half(lg[c]);
      }
      // softmax over c (10 values, registers)
      float m = lg[0];
#pragma unroll
      for (int c = 1; c < Cn; ++c) m = fmaxf(m, lg[c]);
      float e[Cn];
      float ssum = 0.f;
#pragma unroll
      for (int c = 0; c < Cn; ++c) {
        e[c] = __expf(lg[c] - m);
        ssum += e[c];
      }
      const float inv = 1.f / ssum;
#pragma unroll
      for (int c = 0; c < Cn; ++c) {
        const float cv = e[c] * inv;
        float v16[On];
        load_row16(row + c * On, v16); // second read: cache-hot
#pragma unroll
        for (int o = 0; o < On; ++o)
          s_part[c * On + o] = __builtin_fmaf(cv, v16[o], s_part[c * On + o]);
      }
    }
    reduce_squash(s_part, 1.0f, tid, lane, w, s_red, s_lds, v_lds);
  }

  if (tid < ROW) out[(size_t)b * ROW + tid] = v_lds[tid];
}

extern "C" void kernel_launch(void* const* d_in, const int* in_sizes, int n_in,
                              void* d_out, int out_size, void* d_ws, size_t ws_size,
                              hipStream_t stream) {
  (void)in_sizes; (void)n_in; (void)out_size;
  const float* u = (const float*)d_in[0];
  const float* W = (const float*)d_in[1];
  float* out = (float*)d_out;
  __half* uhat = (__half*)d_ws;
  const size_t need = (size_t)Bn * Pn * Cn * On * sizeof(__half);
  if (ws_size < need) return; // needs ~168 MB scratch
  k_uhat<<<Pn, 256, 0, stream>>>(u, W, uhat);
  k_route<<<Bn, TPB, 0, stream>>>(uhat, out);
}

// Round 3
// 284.646 us; speedup vs baseline: 1.9774x; 1.9774x over previous
//
#include <hip/hip_runtime.h>
#include <hip/hip_fp16.h>

// CapsNet dynamic routing, B=256, P=2048, C=10, OUT=16, IN=8, 3 iters.
// K1 (k_uhat): u_hat fp16 -> d_ws, LDS-restaged for write locality.
// K2 (k_route): block=b, lane-pairs split c-space (acc[5][16]=80 VGPR, no
// spill -- R2's s_part[160] + launch_bounds(512,2) forced a full spill:
// WRITE_SIZE was 174MB of scratch). Dots via v_dot2_f32_f16.

#define Bn 256
#define Pn 2048
#define Cn 10
#define On 16
#define In 8
#define ROW 160          // Cn*On
#define TPB 512
#define PAIRS (TPB / 2)  // 256
#define ITERS (Pn / PAIRS) // 8
#define NW (TPB / 64)    // 8 waves
#define CH 5             // c's per half-thread
#define HROW 80          // CH*On

typedef _Float16 h2f __attribute__((ext_vector_type(2)));

// ---------------- k_uhat ----------------
// block=p, thread=b. Two c-half stages so LDS stays at 45KB (3 blocks/CU).
__global__ __launch_bounds__(256) void k_uhat(const float* __restrict__ u,
                                              const float* __restrict__ W,
                                              __half* __restrict__ uhat) {
  __shared__ __half st[256 * 88]; // stride 88 halves = 176B (16B aligned), 45056 B
  const int p = blockIdx.x;
  const int t = threadIdx.x; // = b in compute phase
  const float4* up = reinterpret_cast<const float4*>(u + ((size_t)t * Pn + p) * In);
  float4 a0 = up[0], a1 = up[1];
  const float uu[8] = {a0.x, a0.y, a0.z, a0.w, a1.x, a1.y, a1.z, a1.w};
  const float* wb = W + (size_t)p * (Cn * On * In);

  for (int hf = 0; hf < 2; ++hf) {
    __half* srow = st + t * 88;
#pragma unroll
    for (int kc = 0; kc < CH; ++kc) {
      const int c = hf * CH + kc;
      const float* wr = wb + c * (On * In);
      union { float4 f[2]; __half2 h2[8]; } pk;
#pragma unroll
      for (int o2 = 0; o2 < 8; ++o2) {
        float acc0 = 0.f, acc1 = 0.f;
#pragma unroll
        for (int i = 0; i < In; ++i) {
          acc0 = __builtin_fmaf(wr[(2 * o2) * In + i], uu[i], acc0);
          acc1 = __builtin_fmaf(wr[(2 * o2 + 1) * In + i], uu[i], acc1);
        }
        pk.h2[o2] = __floats2half2_rn(acc0, acc1);
      }
      *reinterpret_cast<float4*>(srow + kc * 16) = pk.f[0];
      *reinterpret_cast<float4*>(srow + kc * 16 + 8) = pk.f[1];
    }
    __syncthreads();
    // write 2560 float4 (256 b-rows x 10 chunks), lanes span ~6 rows/inst
#pragma unroll
    for (int it = 0; it < 10; ++it) {
      const int f = it * 256 + t;
      const int bo = f / 10;
      const int ch = f - bo * 10;
      float4 val = *reinterpret_cast<const float4*>(st + bo * 88 + ch * 8);
      *reinterpret_cast<float4*>(uhat + ((size_t)bo * Pn + p) * ROW + hf * HROW + ch * 8) = val;
    }
    __syncthreads();
  }
}

// ---------------- k_route ----------------
__shared__ __half logits_h[Pn][2][CH]; // dummy decl avoided; real ones inside

__device__ __forceinline__ void reduce_squash(float (&acc)[CH][On], float scale,
                                              int tid, int lane, int w, int h,
                                              float (*s_red)[ROW], float* s_lds,
                                              float* v_lds, __half2 (*v_h2)[8]) {
#pragma unroll
  for (int k = 0; k < HROW; ++k) {
    float x = acc[k >> 4][k & 15];
#pragma unroll
    for (int off = 2; off <= 32; off <<= 1) x += __shfl_xor(x, off, 64);
    if ((lane >> 1) == (k & 31)) s_red[w][h * HROW + k] = x;
  }
  __syncthreads();
  if (tid < ROW) {
    float tsum = 0.f;
#pragma unroll
    for (int ww = 0; ww < NW; ++ww) tsum += s_red[ww][tid];
    s_lds[tid] = scale * tsum;
  }
  __syncthreads();
  if (tid < Cn) {
    float sq = 0.f;
#pragma unroll
    for (int o = 0; o < On; ++o) {
      float x = s_lds[tid * On + o];
      sq += x * x;
    }
    float sc = (sq / (1.f + sq)) / sqrtf(sq + 1e-9f);
#pragma unroll
    for (int o = 0; o < On; ++o) v_lds[tid * On + o] = sc * s_lds[tid * On + o];
#pragma unroll
    for (int o2 = 0; o2 < 8; ++o2)
      v_h2[tid][o2] = __floats2half2_rn(v_lds[tid * On + 2 * o2], v_lds[tid * On + 2 * o2 + 1]);
  }
  __syncthreads();
}

__global__ __launch_bounds__(TPB, 2) void k_route(const __half* __restrict__ uhat,
                                                  float* __restrict__ out) {
  __shared__ __half lg_lds[Pn][2][CH]; // 40960 B
  __shared__ float s_red[NW][ROW];     // 5120 B
  __shared__ float s_lds[ROW];
  __shared__ float v_lds[ROW];
  __shared__ __half2 v_h2[Cn][8];
  const int b = blockIdx.x;
  const int tid = threadIdx.x;
  const int lane = tid & 63;
  const int w = tid >> 6;
  const int h = tid & 1;   // c-half this thread owns
  const int pr = tid >> 1; // pair index in [0,256)
  const __half* base = uhat + (size_t)b * Pn * ROW + h * HROW;

  float acc[CH][On];

  // ---- PASS 1: weights uniform 0.1 ----
#pragma unroll
  for (int kc = 0; kc < CH; ++kc)
#pragma unroll
    for (int o = 0; o < On; ++o) acc[kc][o] = 0.f;
  for (int it = 0; it < ITERS; ++it) {
    const __half* row = base + (size_t)(pr + PAIRS * it) * ROW;
#pragma unroll
    for (int kc = 0; kc < CH; ++kc) {
      union { float4 f[2]; __half hh[16]; } q;
      q.f[0] = *reinterpret_cast<const float4*>(row + kc * 16);
      q.f[1] = *reinterpret_cast<const float4*>(row + kc * 16 + 8);
#pragma unroll
      for (int o = 0; o < On; ++o) acc[kc][o] += __half2float(q.hh[o]);
    }
  }
  reduce_squash(acc, 0.1f, tid, lane, w, h, s_red, s_lds, v_lds, v_h2);

  // ---- PASSES 2,3 ----
  for (int pass = 0; pass < 2; ++pass) {
#pragma unroll
    for (int kc = 0; kc < CH; ++kc)
#pragma unroll
      for (int o = 0; o < On; ++o) acc[kc][o] = 0.f;
    for (int it = 0; it < ITERS; ++it) {
      const int p = pr + PAIRS * it;
      const __half* row = base + (size_t)p * ROW;
      float lg[CH];
#pragma unroll
      for (int kc = 0; kc < CH; ++kc) {
        union { float4 f[2]; h2f hh2[8]; } q;
        q.f[0] = *reinterpret_cast<const float4*>(row + kc * 16);
        q.f[1] = *reinterpret_cast<const float4*>(row + kc * 16 + 8);
        float d = 0.f;
#pragma unroll
        for (int o2 = 0; o2 < 8; ++o2) {
          h2f vv = *reinterpret_cast<const h2f*>(&v_h2[h * CH + kc][o2]); // uniform addr: LDS broadcast
          d = __builtin_amdgcn_fdot2(q.hh2[o2], vv, d, false);
        }
        lg[kc] = (pass == 0) ? d : (d + __half2float(lg_lds[p][h][kc]));
      }
      if (pass == 0) {
#pragma unroll
        for (int kc = 0; kc < CH; ++kc) lg_lds[p][h][kc] = __float2half(lg[kc]);
      }
      // softmax across both halves via 2 shuffles
      float m = lg[0];
#pragma unroll
      for (int kc = 1; kc < CH; ++kc) m = fmaxf(m, lg[kc]);
      m = fmaxf(m, __shfl_xor(m, 1, 64));
      float e[CH], ssum = 0.f;
#pragma unroll
      for (int kc = 0; kc < CH; ++kc) {
        e[kc] = __expf(lg[kc] - m);
        ssum += e[kc];
      }
      ssum += __shfl_xor(ssum, 1, 64);
      const float inv = 1.f / ssum;
#pragma unroll
      for (int kc = 0; kc < CH; ++kc) {
        union { float4 f[2]; __half hh[16]; } q;
        q.f[0] = *reinterpret_cast<const float4*>(row + kc * 16); // L1-hot reload
        q.f[1] = *reinterpret_cast<const float4*>(row + kc * 16 + 8);
        const float cv = e[kc] * inv;
#pragma unroll
        for (int o = 0; o < On; ++o)
          acc[kc][o] = __builtin_fmaf(cv, __half2float(q.hh[o]), acc[kc][o]);
      }
    }
    reduce_squash(acc, 1.0f, tid, lane, w, h, s_red, s_lds, v_lds, v_h2);
  }

  if (tid < ROW) out[(size_t)b * ROW + tid] = v_lds[tid];
}

extern "C" void kernel_launch(void* const* d_in, const int* in_sizes, int n_in,
                              void* d_out, int out_size, void* d_ws, size_t ws_size,
                              hipStream_t stream) {
  (void)in_sizes; (void)n_in; (void)out_size;
  const float* u = (const float*)d_in[0];
  const float* W = (const float*)d_in[1];
  float* out = (float*)d_out;
  __half* uhat = (__half*)d_ws;
  const size_t need = (size_t)Bn * Pn * Cn * On * sizeof(__half);
  if (ws_size < need) return; // needs ~168 MB scratch
  k_uhat<<<Pn, 256, 0, stream>>>(u, W, uhat);
  k_route<<<Bn, TPB, 0, stream>>>(uhat, out);
}